// Round 2
// baseline (1782.664 us; speedup 1.0000x reference)
//
#include <hip/hip_runtime.h>
#include <hip/hip_bf16.h>
#include <stdint.h>

// ---------------- CSR build ----------------

__global__ __launch_bounds__(256) void histogram_kernel(const int* __restrict__ col,
                                                        int* __restrict__ indeg, int E) {
    int i = blockIdx.x * 256 + threadIdx.x;
    if (i < E) atomicAdd(&indeg[col[i]], 1);
}

__global__ __launch_bounds__(256) void dinv_kernel(const int* __restrict__ indeg,
                                                   float* __restrict__ dinv, int N) {
    int i = blockIdx.x * 256 + threadIdx.x;
    if (i < N) dinv[i] = rsqrtf((float)(indeg[i] + 1));  // +1 self-loop; deg>=1 always
}

// Single-block hierarchical scan (wave shfl scan + cross-wave scan). N=50k -> 49 chunks.
__global__ __launch_bounds__(1024) void scan_kernel(const int* __restrict__ cnt,
                                                    int* __restrict__ off, int N) {
    __shared__ int wsum[16];
    __shared__ int wpre[16];
    __shared__ int ctot;
    int tid = threadIdx.x, lane = tid & 63, wid = tid >> 6;
    int carry = 0;
    for (int base = 0; base < N; base += 1024) {
        int i = base + tid;
        int v = (i < N) ? cnt[i] : 0;
        int x = v;
        #pragma unroll
        for (int o = 1; o < 64; o <<= 1) {
            int y = __shfl_up(x, o, 64);
            if (lane >= o) x += y;
        }
        if (lane == 63) wsum[wid] = x;
        __syncthreads();
        if (wid == 0 && lane < 16) {
            int wv = wsum[lane];
            int wx = wv;
            #pragma unroll
            for (int o = 1; o < 16; o <<= 1) {
                int y = __shfl_up(wx, o, 64);
                if (lane >= o) wx += y;
            }
            wpre[lane] = wx - wv;      // exclusive prefix of wave sums
            if (lane == 15) ctot = wx; // chunk total
        }
        __syncthreads();
        if (i < N) off[i] = carry + wpre[wid] + (x - v);  // exclusive scan value
        carry += ctot;
        __syncthreads();  // protect wsum/ctot for next chunk
    }
    if (tid == 0) off[N] = carry;
}

__global__ __launch_bounds__(256) void scatter_csr_kernel(const int* __restrict__ row,
                                                          const int* __restrict__ col,
                                                          const int* __restrict__ off,
                                                          int* __restrict__ fill,
                                                          int* __restrict__ srclist, int E) {
    int i = blockIdx.x * 256 + threadIdx.x;
    if (i < E) {
        int c = col[i];
        int p = atomicAdd(&fill[c], 1);
        srclist[off[c] + p] = row[i];
    }
}

// ---------------- GEMM: out[n][:] = (X[n][:] @ W) * dinv[n] ----------------
// Block: 32 rows x 128 cols, 256 threads, each thread 4 rows x 4 cols.
// W staged in two 64-row K-chunks (32 KB) to stay under the 64 KB LDS/block cap.
__global__ __launch_bounds__(256) void gemm_scale_kernel(const float* __restrict__ X,
                                                         const float* __restrict__ W,
                                                         const float* __restrict__ dinv,
                                                         float* __restrict__ out, int N) {
    __shared__ float ws[64 * 128];   // 32 KB (one K-chunk of W)
    __shared__ float xs[32 * 128];   // 16 KB
    int tid = threadIdx.x;
    int rowbase = blockIdx.x * 32;

    {   // stage X tile (guarded)
        const float4* Xv = (const float4*)(X + (size_t)rowbase * 128);
        float4* xsv = (float4*)xs;
        #pragma unroll
        for (int j = 0; j < 4; j++) {
            int i = tid + j * 256;               // float4 index within tile
            int r = rowbase + (i >> 5);
            float4 z = make_float4(0.f, 0.f, 0.f, 0.f);
            xsv[i] = (r < N) ? Xv[i] : z;
        }
    }

    int cg = tid & 31;   // col group (4 cols)
    int rq = tid >> 5;   // row quad (4 rows)
    float acc[4][4] = {};

    for (int kb = 0; kb < 128; kb += 64) {
        {   // stage W rows kb..kb+63 (hot in L2 across blocks)
            const float4* Wv = (const float4*)(W + kb * 128);
            float4* wsv = (float4*)ws;
            #pragma unroll
            for (int i = 0; i < 8; i++) wsv[tid + i * 256] = Wv[tid + i * 256];
        }
        __syncthreads();   // covers ws stage (and xs stage on first iter)

        for (int k = 0; k < 64; k += 4) {
            float4 a[4];
            #pragma unroll
            for (int r = 0; r < 4; r++) a[r] = *(const float4*)&xs[(rq * 4 + r) * 128 + kb + k];
            #pragma unroll
            for (int kk = 0; kk < 4; kk++) {
                float4 b = *(const float4*)&ws[(k + kk) * 128 + cg * 4];
                #pragma unroll
                for (int r = 0; r < 4; r++) {
                    float av = (kk == 0) ? a[r].x : (kk == 1) ? a[r].y : (kk == 2) ? a[r].z : a[r].w;
                    acc[r][0] = fmaf(av, b.x, acc[r][0]);
                    acc[r][1] = fmaf(av, b.y, acc[r][1]);
                    acc[r][2] = fmaf(av, b.z, acc[r][2]);
                    acc[r][3] = fmaf(av, b.w, acc[r][3]);
                }
            }
        }
        __syncthreads();   // before restaging ws
    }

    #pragma unroll
    for (int r = 0; r < 4; r++) {
        int rown = rowbase + rq * 4 + r;
        if (rown < N) {
            float s = dinv[rown];
            float4 o = make_float4(acc[r][0] * s, acc[r][1] * s, acc[r][2] * s, acc[r][3] * s);
            *(float4*)&out[(size_t)rown * 128 + cg * 4] = o;
        }
    }
}

// ---------------- Aggregation (pull mode): one wave per node ----------------
// out[c][:] = relu(dinv[c] * (hs[c][:] + sum_{r in in(c)} hs[r][:]) + bias)
__global__ __launch_bounds__(256) void aggregate_kernel(const float* __restrict__ hs,
                                                        const int* __restrict__ off,
                                                        const int* __restrict__ srclist,
                                                        const float* __restrict__ dinv,
                                                        const float* __restrict__ bias,
                                                        float* __restrict__ out, int N) {
    int wave = (blockIdx.x * 256 + threadIdx.x) >> 6;
    int lane = threadIdx.x & 63;
    if (wave >= N) return;
    int c = wave;
    float2 acc = *(const float2*)&hs[(size_t)c * 128 + lane * 2];  // self-loop term
    float2 acc2 = make_float2(0.f, 0.f);
    int s0 = off[c], s1 = off[c + 1];
    int i = s0;
    for (; i + 1 < s1; i += 2) {  // unroll-2 for load ILP
        int sa = srclist[i];
        int sb = srclist[i + 1];
        float2 va = *(const float2*)&hs[(size_t)sa * 128 + lane * 2];
        float2 vb = *(const float2*)&hs[(size_t)sb * 128 + lane * 2];
        acc.x += va.x;  acc.y += va.y;
        acc2.x += vb.x; acc2.y += vb.y;
    }
    if (i < s1) {
        int sa = srclist[i];
        float2 va = *(const float2*)&hs[(size_t)sa * 128 + lane * 2];
        acc.x += va.x; acc.y += va.y;
    }
    acc.x += acc2.x; acc.y += acc2.y;
    float d = dinv[c];
    float2 b = *(const float2*)&bias[lane * 2];
    float2 o;
    o.x = fmaxf(fmaf(acc.x, d, b.x), 0.f);
    o.y = fmaxf(fmaf(acc.y, d, b.y), 0.f);
    *(float2*)&out[(size_t)c * 128 + lane * 2] = o;
}

// ---------------- Mean pool over sorted batch ids ----------------
#define POOL_NODES 512
__global__ __launch_bounds__(128) void pool_kernel(const float* __restrict__ h,
                                                   const int* __restrict__ batch,
                                                   float* __restrict__ sums,
                                                   float* __restrict__ cnt, int N) {
    int t = threadIdx.x;  // feature id
    int n0 = blockIdx.x * POOL_NODES;
    if (n0 >= N) return;
    int n1 = min(n0 + POOL_NODES, N);
    int g = batch[n0];
    float acc = 0.f, c = 0.f;
    for (int n = n0; n < n1; n++) {
        int gn = batch[n];  // broadcast load
        if (gn != g) {      // batch sorted -> few flushes per block
            atomicAdd(&sums[g * 128 + t], acc);
            if (t == 0) atomicAdd(&cnt[g], c);
            acc = 0.f; c = 0.f; g = gn;
        }
        acc += h[(size_t)n * 128 + t];
        c += 1.f;
    }
    atomicAdd(&sums[g * 128 + t], acc);
    if (t == 0) atomicAdd(&cnt[g], c);
}

// ---------------- Head: out[g] = dot(sums[g]/max(cnt,1), Wc) + bc ----------------
__global__ __launch_bounds__(64) void head_kernel(const float* __restrict__ sums,
                                                  const float* __restrict__ cnt,
                                                  const float* __restrict__ Wc,
                                                  const float* __restrict__ bc,
                                                  float* __restrict__ out) {
    int g = blockIdx.x, lane = threadIdx.x;
    float c = fmaxf(cnt[g], 1.f);
    float2 s = *(const float2*)&sums[g * 128 + lane * 2];
    float2 w = *(const float2*)&Wc[lane * 2];
    float v = (s.x * w.x + s.y * w.y) / c;
    #pragma unroll
    for (int o = 32; o > 0; o >>= 1) v += __shfl_down(v, o, 64);
    if (lane == 0) out[g] = v + bc[0];
}

extern "C" void kernel_launch(void* const* d_in, const int* in_sizes, int n_in,
                              void* d_out, int out_size, void* d_ws, size_t ws_size,
                              hipStream_t stream) {
    const float* x    = (const float*)d_in[0];
    const int*   edge = (const int*)d_in[1];   // [2][E], row-major
    const int*   batch= (const int*)d_in[2];
    const float* W1   = (const float*)d_in[3];
    const float* b1   = (const float*)d_in[4];
    const float* W2   = (const float*)d_in[5];
    const float* b2   = (const float*)d_in[6];
    const float* Wc   = (const float*)d_in[7];
    const float* bc   = (const float*)d_in[8];
    float* out = (float*)d_out;

    int N = in_sizes[0] / 128;
    int E = in_sizes[1] / 2;
    const int* row = edge;
    const int* col = edge + E;

    // workspace layout: [indeg N][fill N][sums 8192][cnt 64] | off | dinv | srclist | bufA | bufB
    char* p = (char*)d_ws;
    int*   indeg   = (int*)p;   p += (size_t)N * 4;
    int*   fill    = (int*)p;   p += (size_t)N * 4;
    float* sums    = (float*)p; p += 64 * 128 * 4;
    float* cntg    = (float*)p; p += 64 * 4;
    size_t zero_bytes = (size_t)(p - (char*)d_ws);
    int*   off     = (int*)p;   p += (size_t)(N + 1) * 4;
    float* dinv    = (float*)p; p += (size_t)N * 4;
    int*   srclist = (int*)p;   p += (size_t)E * 4;
    p = (char*)(((uintptr_t)p + 511) & ~(uintptr_t)511);
    float* bufA    = (float*)p; p += (size_t)N * 128 * 4;
    float* bufB    = (float*)p;

    hipMemsetAsync(d_ws, 0, zero_bytes, stream);  // indeg, fill, sums, cnt

    histogram_kernel<<<(E + 255) / 256, 256, 0, stream>>>(col, indeg, E);
    dinv_kernel<<<(N + 255) / 256, 256, 0, stream>>>(indeg, dinv, N);
    scan_kernel<<<1, 1024, 0, stream>>>(indeg, off, N);
    scatter_csr_kernel<<<(E + 255) / 256, 256, 0, stream>>>(row, col, off, fill, srclist, E);

    // Layer 1
    gemm_scale_kernel<<<(N + 31) / 32, 256, 0, stream>>>(x, W1, dinv, bufA, N);
    aggregate_kernel<<<(N + 3) / 4, 256, 0, stream>>>(bufA, off, srclist, dinv, b1, bufB, N);
    // Layer 2
    gemm_scale_kernel<<<(N + 31) / 32, 256, 0, stream>>>(bufB, W2, dinv, bufA, N);
    aggregate_kernel<<<(N + 3) / 4, 256, 0, stream>>>(bufA, off, srclist, dinv, b2, bufB, N);

    // Pool + head
    pool_kernel<<<(N + POOL_NODES - 1) / POOL_NODES, 128, 0, stream>>>(bufB, batch, sums, cntg, N);
    head_kernel<<<64, 64, 0, stream>>>(sums, cntg, Wc, bc, out);
}